// Round 1
// baseline (67919.476 us; speedup 1.0000x reference)
//
#include <hip/hip_runtime.h>
#include <stdint.h>
#include <stddef.h>

typedef _Float16 half_t;
typedef __attribute__((ext_vector_type(4))) float f32x4;
typedef __attribute__((ext_vector_type(8))) _Float16 f16x8;

#define NWG_REC 128

__device__ __forceinline__ float sigmoidf_(float x) { return 1.f / (1.f + __expf(-x)); }
__device__ __forceinline__ float tanhf_(float x) { return 1.f - 2.f / (__expf(2.f * x) + 1.f); }

// ---------------- weight convert + transpose: in f32 [K][4096] -> out f16 [4096][K] ----------
__global__ void wconv_t(const float* __restrict__ in, half_t* __restrict__ out, int K) {
    __shared__ float tile[32][33];
    int z = blockIdx.z;
    in  += (size_t)z * K * 4096;
    out += (size_t)z * 4096 * K;
    int n0 = blockIdx.x * 32, k0 = blockIdx.y * 32;
    int tx = threadIdx.x, ty = threadIdx.y;  // 32 x 8
#pragma unroll
    for (int i = 0; i < 4; ++i)
        tile[ty + i * 8][tx] = in[(size_t)(k0 + ty + i * 8) * 4096 + n0 + tx];
    __syncthreads();
#pragma unroll
    for (int i = 0; i < 4; ++i)
        out[(size_t)(n0 + ty + i * 8) * K + k0 + tx] = (half_t)tile[tx][ty + i * 8];
}

// ---------------- zero the step counters ----------------
__global__ void init_cnt(int* cnt, int n) {
    int i = blockIdx.x * blockDim.x + threadIdx.x;
    if (i < n) cnt[i] = 0;
}

// ---------------- h0 (f32) -> h_buf parity0 (f16) ----------------
__global__ void hinit(const float* __restrict__ h0l, half_t* __restrict__ h_buf) {
    int i = blockIdx.x * blockDim.x + threadIdx.x;  // 32768
    h_buf[i] = (half_t)h0l[i];
}

// ---------------- input-projection GEMM: Zx[r][n] = sum_k A[r][k] * WT[n][k] ----------------
// amode 0: A = x f32 [B=32][T=512][512], row r -> (b=r&31, t=r>>5)
// amode 1: A = hs f16 [16384][1024]
__global__ void __launch_bounds__(256) xproj_gemm(const void* __restrict__ Ain, int amode,
                                                  const half_t* __restrict__ WT, int Kfull,
                                                  int Din, half_t* __restrict__ Zx) {
    __shared__ half_t As[128 * 72];
    __shared__ half_t Bs[128 * 72];
    const int tid = threadIdx.x;
    const int m0 = blockIdx.y * 128, n0 = blockIdx.x * 128;
    const int lane = tid & 63, wid = tid >> 6;
    const int mw = (wid & 1) * 64, nw = (wid >> 1) * 64;
    const int lm = lane & 15, lk = (lane >> 4) * 8;
    const int sr = tid >> 1;          // staging row 0..127
    const int sk = (tid & 1) * 32;    // staging k offset

    f32x4 acc[4][4];
#pragma unroll
    for (int i = 0; i < 4; ++i)
#pragma unroll
        for (int j = 0; j < 4; ++j) acc[i][j] = (f32x4){0.f, 0.f, 0.f, 0.f};

    for (int k0 = 0; k0 < Din; k0 += 64) {
        // ---- stage A tile [128][64] ----
        if (amode == 0) {
            int r = m0 + sr;
            int bb = r & 31, tt = r >> 5;
            const float* src = (const float*)Ain + ((size_t)bb * 512 + tt) * 512 + k0 + sk;
            half_t* dst = As + sr * 72 + sk;
#pragma unroll
            for (int i = 0; i < 32; i += 8) {
                float4 v0 = *(const float4*)(src + i);
                float4 v1 = *(const float4*)(src + i + 4);
                half_t tmp[8] = {(half_t)v0.x, (half_t)v0.y, (half_t)v0.z, (half_t)v0.w,
                                 (half_t)v1.x, (half_t)v1.y, (half_t)v1.z, (half_t)v1.w};
                *(int4*)(dst + i) = *(int4*)tmp;
            }
        } else {
            const half_t* src = (const half_t*)Ain + (size_t)(m0 + sr) * 1024 + k0 + sk;
            half_t* dst = As + sr * 72 + sk;
#pragma unroll
            for (int i = 0; i < 32; i += 8) *(int4*)(dst + i) = *(const int4*)(src + i);
        }
        // ---- stage B tile [128][64] from WT rows n ----
        {
            const half_t* src = WT + (size_t)(n0 + sr) * Kfull + k0 + sk;
            half_t* dst = Bs + sr * 72 + sk;
#pragma unroll
            for (int i = 0; i < 32; i += 8) *(int4*)(dst + i) = *(const int4*)(src + i);
        }
        __syncthreads();
#pragma unroll
        for (int kk = 0; kk < 64; kk += 32) {
            f16x8 af[4], bfr[4];
#pragma unroll
            for (int i = 0; i < 4; ++i)
                af[i] = *(const f16x8*)(As + (mw + i * 16 + lm) * 72 + kk + lk);
#pragma unroll
            for (int j = 0; j < 4; ++j)
                bfr[j] = *(const f16x8*)(Bs + (nw + j * 16 + lm) * 72 + kk + lk);
#pragma unroll
            for (int i = 0; i < 4; ++i)
#pragma unroll
                for (int j = 0; j < 4; ++j)
                    acc[i][j] = __builtin_amdgcn_mfma_f32_16x16x32_f16(af[i], bfr[j], acc[i][j], 0, 0, 0);
        }
        __syncthreads();
    }
    // ---- epilogue: store f16 ----
#pragma unroll
    for (int i = 0; i < 4; ++i) {
        int row0 = m0 + mw + i * 16 + (lane >> 4) * 4;
#pragma unroll
        for (int j = 0; j < 4; ++j) {
            int col = n0 + nw + j * 16 + lm;
#pragma unroll
            for (int r = 0; r < 4; ++r)
                Zx[(size_t)(row0 + r) * 4096 + col] = (half_t)acc[i][j][r];
        }
    }
}

// ---------------- persistent recurrence kernel (one layer, 512 steps) ----------------
// 128 WGs x 256 threads. WG wg owns h-columns [wg*8, wg*8+8) for all 4 gates (32 z-cols).
__global__ void lstm_rec(const half_t* __restrict__ WT, int Kfull, int Din,
                         const float* __restrict__ bias, const half_t* __restrict__ Zx,
                         const float* __restrict__ c0l, half_t* __restrict__ h_buf,
                         half_t* __restrict__ hs_out, int* __restrict__ cnt) {
    extern __shared__ char smem[];
    half_t* wt  = (half_t*)smem;              // [32][1032]
    half_t* hst = wt + 32 * 1032;             // [32][1032]
    float*  zbuf = (float*)(hst + 32 * 1032); // [32][33]

    const int tid = threadIdx.x;
    const int wg = blockIdx.x;  // 0..127

    // ---- load recurrent weight slice into LDS (once) ----
    {
        int np = tid >> 3;  // 0..31 : n' = g*8 + jp
        int g = np >> 3, jp = np & 7;
        const half_t* src = WT + (size_t)(g * 1024 + wg * 8 + jp) * Kfull + Din;
        half_t* dst = wt + np * 1032;
        int kb = (tid & 7) * 128;
#pragma unroll
        for (int c = 0; c < 128; c += 8)
            *(int4*)(dst + kb + c) = *(const int4*)(src + kb + c);
    }

    // ---- per-thread gate mapping ----
    const int b = tid & 31;
    const int jp = tid >> 5;  // 0..7
    const int col0 = wg * 8 + jp;
    float c_reg = c0l[b * 1024 + col0];
    const float bi = bias[col0], bf = bias[1024 + col0];
    const float bg = bias[2048 + col0], bo = bias[3072 + col0];

    // ---- MFMA lane mapping ----
    const int lane = tid & 63, wid = tid >> 6;
    const int mt = wid & 1, nt = wid >> 1;
    const half_t* aptr = hst + (mt * 16 + (lane & 15)) * 1032 + (lane >> 4) * 8;
    const half_t* bptr = wt + (nt * 16 + (lane & 15)) * 1032 + (lane >> 4) * 8;
    const int crow0 = mt * 16 + (lane >> 4) * 4;
    const int ccol = nt * 16 + (lane & 15);

    for (int t = 0; t < 512; ++t) {
        const int par = t & 1;
        // ---- stage h_prev into LDS (64 KB) ----
        {
            const half_t* src = h_buf + par * 32768;
#pragma unroll
            for (int i = 0; i < 16; ++i) {
                int c = tid + i * 256;          // 0..4095 chunks of 8 halfs
                int hb = c >> 7, kc = (c & 127) << 3;
                *(int4*)(hst + hb * 1032 + kc) = *(const int4*)(src + hb * 1024 + kc);
            }
        }
        __syncthreads();
        // ---- z tile [32 rows x 32 cols] via MFMA, K=1024 ----
        f32x4 acc = (f32x4){0.f, 0.f, 0.f, 0.f};
#pragma unroll 8
        for (int ks = 0; ks < 32; ++ks) {
            f16x8 a = *(const f16x8*)(aptr + ks * 32);
            f16x8 bb = *(const f16x8*)(bptr + ks * 32);
            acc = __builtin_amdgcn_mfma_f32_16x16x32_f16(a, bb, acc, 0, 0, 0);
        }
#pragma unroll
        for (int r = 0; r < 4; ++r) zbuf[(crow0 + r) * 33 + ccol] = acc[r];
        __syncthreads();
        // ---- gates ----
        const half_t* zx = Zx + ((size_t)t * 32 + b) * 4096 + col0;
        float zi = zbuf[b * 33 + jp]      + (float)zx[0]    + bi;
        float zf = zbuf[b * 33 + 8 + jp]  + (float)zx[1024] + bf;
        float zg = zbuf[b * 33 + 16 + jp] + (float)zx[2048] + bg;
        float zo = zbuf[b * 33 + 24 + jp] + (float)zx[3072] + bo;
        c_reg = sigmoidf_(zf) * c_reg + sigmoidf_(zi) * tanhf_(zg);
        float h = sigmoidf_(zo) * tanhf_(c_reg);
        half_t hh = (half_t)h;
        h_buf[(par ^ 1) * 32768 + b * 1024 + col0] = hh;
        hs_out[((size_t)t * 32 + b) * 1024 + col0] = hh;
        // ---- grid barrier (skip after last step) ----
        if (t < 511) {
            __threadfence();
            __syncthreads();
            if (tid == 0) {
                __hip_atomic_fetch_add(cnt + t, 1, __ATOMIC_ACQ_REL, __HIP_MEMORY_SCOPE_AGENT);
                while (__hip_atomic_load(cnt + t, __ATOMIC_ACQUIRE, __HIP_MEMORY_SCOPE_AGENT) < NWG_REC) {}
            }
            __syncthreads();
            __threadfence();
        }
    }
}

// ---------------- head: out[b][o] = sum_k h_last[b][k] * Wout[k][o] + bout[o] ----------------
__global__ void head_gemm(const half_t* __restrict__ hs, const float* __restrict__ Wout,
                          const float* __restrict__ bout, float* __restrict__ out) {
    int o = blockIdx.x * 32 + (threadIdx.x & 31);
    int b = blockIdx.y * 8 + (threadIdx.x >> 5);
    const half_t* h = hs + ((size_t)511 * 32 + b) * 1024;
    float acc = 0.f;
#pragma unroll 4
    for (int k = 0; k < 1024; ++k) acc += (float)h[k] * Wout[(size_t)k * 1024 + o];
    out[b * 1024 + o] = acc + bout[o];
}

extern "C" void kernel_launch(void* const* d_in, const int* in_sizes, int n_in,
                              void* d_out, int out_size, void* d_ws, size_t ws_size,
                              hipStream_t stream) {
    const float* x    = (const float*)d_in[0];
    const float* h0   = (const float*)d_in[1];
    const float* c0   = (const float*)d_in[2];
    const float* W0   = (const float*)d_in[3];
    const float* b0   = (const float*)d_in[4];
    const float* Wl   = (const float*)d_in[5];
    const float* bl   = (const float*)d_in[6];
    const float* Wout = (const float*)d_in[7];
    const float* bout = (const float*)d_in[8];
    float* out = (float*)d_out;

    char* ws = (char*)d_ws;
    size_t off = 0;
    auto alloc = [&](size_t bytes) {
        size_t r = off;
        off = (off + bytes + 255) & ~(size_t)255;
        return r;
    };
    half_t* WT0   = (half_t*)(ws + alloc((size_t)4096 * 1536 * 2));
    half_t* WT123 = (half_t*)(ws + alloc((size_t)3 * 4096 * 2048 * 2));
    half_t* Zx    = (half_t*)(ws + alloc((size_t)16384 * 4096 * 2));
    half_t* hsA   = (half_t*)(ws + alloc((size_t)16384 * 1024 * 2));
    half_t* hsB   = (half_t*)(ws + alloc((size_t)16384 * 1024 * 2));
    half_t* h_buf = (half_t*)(ws + alloc((size_t)2 * 32 * 1024 * 2));
    int*    cnt   = (int*)(ws + alloc((size_t)4 * 512 * 4));

    // weight converts (every call; inputs are restored each call)
    wconv_t<<<dim3(128, 48, 1), dim3(32, 8), 0, stream>>>(W0, WT0, 1536);
    wconv_t<<<dim3(128, 64, 3), dim3(32, 8), 0, stream>>>(Wl, WT123, 2048);
    init_cnt<<<8, 256, 0, stream>>>(cnt, 2048);

    const size_t recLds = (size_t)(2 * 32 * 1032) * 2 + (size_t)32 * 33 * 4;  // 136320 B

    half_t* hs_bufs[2] = {hsA, hsB};
    const void* cur_in = (const void*)x;
    for (int l = 0; l < 4; ++l) {
        const half_t* WTl = (l == 0) ? WT0 : (WT123 + (size_t)(l - 1) * 4096 * 2048);
        int Kfull = (l == 0) ? 1536 : 2048;
        int Din = (l == 0) ? 512 : 1024;
        const float* bias = (l == 0) ? b0 : (bl + (size_t)(l - 1) * 4096);
        half_t* hs_out = hs_bufs[l & 1];  // l0->A, l1->B, l2->A, l3->B

        hinit<<<128, 256, 0, stream>>>(h0 + (size_t)l * 32768, h_buf);
        xproj_gemm<<<dim3(32, 128), 256, 0, stream>>>(cur_in, (l == 0) ? 0 : 1, WTl, Kfull, Din, Zx);
        lstm_rec<<<NWG_REC, 256, recLds, stream>>>(WTl, Kfull, Din, bias, Zx,
                                                   c0 + (size_t)l * 32768, h_buf, hs_out,
                                                   cnt + (size_t)l * 512);
        cur_in = (const void*)hs_out;
    }
    head_gemm<<<dim3(32, 4), 256, 0, stream>>>(hs_bufs[1], Wout, bout, out);
}

// Round 2
// 26809.653 us; speedup vs baseline: 2.5334x; 2.5334x over previous
//
#include <hip/hip_runtime.h>
#include <stdint.h>
#include <stddef.h>

typedef _Float16 half_t;
typedef __attribute__((ext_vector_type(4))) float f32x4;
typedef __attribute__((ext_vector_type(8))) _Float16 f16x8;

#define NWG_REC 128

__device__ __forceinline__ float sigmoidf_(float x) { return 1.f / (1.f + __expf(-x)); }
__device__ __forceinline__ float tanhf_(float x) { return 1.f - 2.f / (__expf(2.f * x) + 1.f); }

// ---------------- weight convert + transpose: in f32 [K][4096] -> out f16 [4096][K] ----------
__global__ void wconv_t(const float* __restrict__ in, half_t* __restrict__ out, int K) {
    __shared__ float tile[32][33];
    int z = blockIdx.z;
    in  += (size_t)z * K * 4096;
    out += (size_t)z * 4096 * K;
    int n0 = blockIdx.x * 32, k0 = blockIdx.y * 32;
    int tx = threadIdx.x, ty = threadIdx.y;  // 32 x 8
#pragma unroll
    for (int i = 0; i < 4; ++i)
        tile[ty + i * 8][tx] = in[(size_t)(k0 + ty + i * 8) * 4096 + n0 + tx];
    __syncthreads();
#pragma unroll
    for (int i = 0; i < 4; ++i)
        out[(size_t)(n0 + ty + i * 8) * K + k0 + tx] = (half_t)tile[tx][ty + i * 8];
}

// ---------------- zero the step counters ----------------
__global__ void init_cnt(int* cnt, int n) {
    int i = blockIdx.x * blockDim.x + threadIdx.x;
    if (i < n) cnt[i] = 0;
}

// ---------------- h0 (f32) -> h_buf parity0 (f16), WG-blocked layout [wg][b][jp] ------------
__global__ void hinit(const float* __restrict__ h0l, half_t* __restrict__ h_buf) {
    int i = blockIdx.x * blockDim.x + threadIdx.x;  // 0..32767 dest index
    int wgp = i >> 8, bp = (i >> 3) & 31, jp = i & 7;
    h_buf[i] = (half_t)h0l[bp * 1024 + wgp * 8 + jp];
}

// ---------------- input-projection GEMM: Z[r][n] = sum_k A[r][k] * WT[n][k] ----------------
// amode 0: A = x f32 [B=32][T=512][512], row r -> (b=r&31, t=r>>5)
// amode 1: A = hs f16 WG-blocked [T][128][32][8]  (row r -> t=r>>5, b=r&31)
// Zx output: blocked [t][g(4)][wg(128)][b(32)][jp(8)]
__global__ void __launch_bounds__(256) xproj_gemm(const void* __restrict__ Ain, int amode,
                                                  const half_t* __restrict__ WT, int Kfull,
                                                  int Din, half_t* __restrict__ Zx) {
    __shared__ half_t As[128 * 72];
    __shared__ half_t Bs[128 * 72];
    const int tid = threadIdx.x;
    const int m0 = blockIdx.y * 128, n0 = blockIdx.x * 128;
    const int lane = tid & 63, wid = tid >> 6;
    const int mw = (wid & 1) * 64, nw = (wid >> 1) * 64;
    const int lm = lane & 15, lk = (lane >> 4) * 8;
    const int sr = tid >> 1;          // staging row 0..127
    const int sk = (tid & 1) * 32;    // staging k offset

    f32x4 acc[4][4];
#pragma unroll
    for (int i = 0; i < 4; ++i)
#pragma unroll
        for (int j = 0; j < 4; ++j) acc[i][j] = (f32x4){0.f, 0.f, 0.f, 0.f};

    for (int k0 = 0; k0 < Din; k0 += 64) {
        // ---- stage A tile [128][64] ----
        if (amode == 0) {
            int r = m0 + sr;
            int bb = r & 31, tt = r >> 5;
            const float* src = (const float*)Ain + ((size_t)bb * 512 + tt) * 512 + k0 + sk;
            half_t* dst = As + sr * 72 + sk;
#pragma unroll
            for (int i = 0; i < 32; i += 8) {
                float4 v0 = *(const float4*)(src + i);
                float4 v1 = *(const float4*)(src + i + 4);
                half_t tmp[8] = {(half_t)v0.x, (half_t)v0.y, (half_t)v0.z, (half_t)v0.w,
                                 (half_t)v1.x, (half_t)v1.y, (half_t)v1.z, (half_t)v1.w};
                *(int4*)(dst + i) = *(int4*)tmp;
            }
        } else {
            int r = m0 + sr;
            int tt = r >> 5, bb = r & 31;
            const half_t* src = (const half_t*)Ain + (size_t)tt * 32768 +
                                (size_t)((k0 + sk) >> 3) * 256 + bb * 8;
            half_t* dst = As + sr * 72 + sk;
#pragma unroll
            for (int w = 0; w < 4; ++w) *(int4*)(dst + w * 8) = *(const int4*)(src + w * 256);
        }
        // ---- stage B tile [128][64] from WT rows n ----
        {
            const half_t* src = WT + (size_t)(n0 + sr) * Kfull + k0 + sk;
            half_t* dst = Bs + sr * 72 + sk;
#pragma unroll
            for (int i = 0; i < 32; i += 8) *(int4*)(dst + i) = *(const int4*)(src + i);
        }
        __syncthreads();
#pragma unroll
        for (int kk = 0; kk < 64; kk += 32) {
            f16x8 af[4], bfr[4];
#pragma unroll
            for (int i = 0; i < 4; ++i)
                af[i] = *(const f16x8*)(As + (mw + i * 16 + lm) * 72 + kk + lk);
#pragma unroll
            for (int j = 0; j < 4; ++j)
                bfr[j] = *(const f16x8*)(Bs + (nw + j * 16 + lm) * 72 + kk + lk);
#pragma unroll
            for (int i = 0; i < 4; ++i)
#pragma unroll
                for (int j = 0; j < 4; ++j)
                    acc[i][j] = __builtin_amdgcn_mfma_f32_16x16x32_f16(af[i], bfr[j], acc[i][j], 0, 0, 0);
        }
        __syncthreads();
    }
    // ---- epilogue: store f16 into blocked Zx ----
#pragma unroll
    for (int i = 0; i < 4; ++i) {
        int row0 = m0 + mw + i * 16 + (lane >> 4) * 4;
#pragma unroll
        for (int j = 0; j < 4; ++j) {
            int col = n0 + nw + j * 16 + lm;
            int g = col >> 10, jj = col & 1023;
            int wgp = jj >> 3, jp2 = jj & 7;
#pragma unroll
            for (int r = 0; r < 4; ++r) {
                int row = row0 + r;
                size_t idx = (((size_t)(row >> 5) * 4 + g) * 128 + wgp) * 256 +
                             (size_t)(row & 31) * 8 + jp2;
                Zx[idx] = (half_t)acc[i][j][r];
            }
        }
    }
}

// ---------------- persistent recurrence kernel (one layer, 512 steps) ----------------
// 128 WGs x 256 threads. WG wg owns h-columns [wg*8, wg*8+8) for all 4 gates.
// h_buf: 2 x [128 wg][32 b][8 jp] f16.  Zx: [t][g][wg][b][jp].  hs_out: [t][wg][b][jp].
__global__ void lstm_rec(const half_t* __restrict__ WT, int Kfull, int Din,
                         const float* __restrict__ bias, const half_t* __restrict__ Zx,
                         const float* __restrict__ c0l, half_t* __restrict__ h_buf,
                         half_t* __restrict__ hs_out, int* __restrict__ cnt) {
    extern __shared__ char smem[];
    half_t* wt  = (half_t*)smem;              // [32][1032]
    half_t* hst = wt + 32 * 1032;             // [32][1032]
    float*  zbuf = (float*)(hst + 32 * 1032); // [32][33]

    const int tid = threadIdx.x;
    const int wg = blockIdx.x;  // 0..127

    // ---- load recurrent weight slice into LDS (once) ----
    {
        int np = tid >> 3;  // 0..31 : n' = g*8 + jp
        int g = np >> 3, jp = np & 7;
        const half_t* src = WT + (size_t)(g * 1024 + wg * 8 + jp) * Kfull + Din;
        half_t* dst = wt + np * 1032;
        int kb = (tid & 7) * 128;
#pragma unroll
        for (int c = 0; c < 128; c += 8)
            *(int4*)(dst + kb + c) = *(const int4*)(src + kb + c);
    }

    // ---- per-thread gate mapping ----
    const int b = tid & 31;
    const int jp = tid >> 5;  // 0..7
    const int col0 = wg * 8 + jp;
    float c_reg = c0l[b * 1024 + col0];
    const float bi = bias[col0], bf = bias[1024 + col0];
    const float bg = bias[2048 + col0], bo = bias[3072 + col0];

    // ---- MFMA lane mapping ----
    const int lane = tid & 63, wid = tid >> 6;
    const int mt = wid & 1, nt = wid >> 1;
    const half_t* aptr = hst + (mt * 16 + (lane & 15)) * 1032 + (lane >> 4) * 8;
    const half_t* bptr = wt + (nt * 16 + (lane & 15)) * 1032 + (lane >> 4) * 8;
    const int crow0 = mt * 16 + (lane >> 4) * 4;
    const int ccol = nt * 16 + (lane & 15);

    for (int t = 0; t < 512; ++t) {
        const int par = t & 1;
        // ---- prefetch this step's Zx gate values (independent of barrier/h) ----
        const half_t* zxb = Zx + ((size_t)t * 512 + wg) * 256 + b * 8 + jp;
        float pzi = (float)zxb[0];
        float pzf = (float)zxb[32768];
        float pzg = (float)zxb[65536];
        float pzo = (float)zxb[98304];
        // ---- stage h_prev into LDS (64 KB), blocked -> [b][k] ----
        {
            const half_t* src = h_buf + par * 32768;
#pragma unroll
            for (int i = 0; i < 16; ++i) {
                int c = tid + i * 256;          // 0..4095 chunks of 8 halfs
                int wgp = c >> 5, bp = c & 31;
                *(int4*)(hst + bp * 1032 + wgp * 8) = *(const int4*)(src + (size_t)c * 8);
            }
        }
        __syncthreads();
        // ---- z tile [32 rows x 32 cols] via MFMA, K=1024 ----
        f32x4 acc = (f32x4){0.f, 0.f, 0.f, 0.f};
#pragma unroll 8
        for (int ks = 0; ks < 32; ++ks) {
            f16x8 a = *(const f16x8*)(aptr + ks * 32);
            f16x8 bb = *(const f16x8*)(bptr + ks * 32);
            acc = __builtin_amdgcn_mfma_f32_16x16x32_f16(a, bb, acc, 0, 0, 0);
        }
#pragma unroll
        for (int r = 0; r < 4; ++r) zbuf[(crow0 + r) * 33 + ccol] = acc[r];
        __syncthreads();
        // ---- gates ----
        float zi = zbuf[b * 33 + jp]      + pzi + bi;
        float zf = zbuf[b * 33 + 8 + jp]  + pzf + bf;
        float zg = zbuf[b * 33 + 16 + jp] + pzg + bg;
        float zo = zbuf[b * 33 + 24 + jp] + pzo + bo;
        c_reg = sigmoidf_(zf) * c_reg + sigmoidf_(zi) * tanhf_(zg);
        float h = sigmoidf_(zo) * tanhf_(c_reg);
        half_t hh = (half_t)h;
        int hidx = wg * 256 + b * 8 + jp;
        h_buf[(par ^ 1) * 32768 + hidx] = hh;
        hs_out[(size_t)t * 32768 + hidx] = hh;
        // ---- grid barrier (skip after last step) ----
        if (t < 511) {
            __syncthreads();   // drains each wave's stores to L2 (vmcnt 0)
            if (tid == 0) {
                int* c_t = cnt + (size_t)t * 16;
                __hip_atomic_fetch_add(c_t, 1, __ATOMIC_RELEASE, __HIP_MEMORY_SCOPE_AGENT);
                while (__hip_atomic_load(c_t, __ATOMIC_RELAXED, __HIP_MEMORY_SCOPE_AGENT) < NWG_REC) {
                    __builtin_amdgcn_s_sleep(4);
                }
            }
            __syncthreads();
            __builtin_amdgcn_fence(__ATOMIC_ACQUIRE, "agent");
        }
    }
}

// ---------------- head: out[b][o] = sum_k h_last[b][k] * Wout[k][o] + bout[o] ----------------
// hs blocked: h_last[b][k] at hs + 511*32768 + (k>>3)*256 + b*8 + (k&7)
__global__ void head_gemm(const half_t* __restrict__ hs, const float* __restrict__ Wout,
                          const float* __restrict__ bout, float* __restrict__ out) {
    int o = blockIdx.x * 32 + (threadIdx.x & 31);
    int b = blockIdx.y * 8 + (threadIdx.x >> 5);
    const half_t* h = hs + (size_t)511 * 32768 + b * 8;
    float acc = 0.f;
    for (int kb = 0; kb < 128; ++kb) {
        const half_t* hp = h + (size_t)kb * 256;
#pragma unroll
        for (int j = 0; j < 8; ++j)
            acc += (float)hp[j] * Wout[(size_t)(kb * 8 + j) * 1024 + o];
    }
    out[b * 1024 + o] = acc + bout[o];
}

extern "C" void kernel_launch(void* const* d_in, const int* in_sizes, int n_in,
                              void* d_out, int out_size, void* d_ws, size_t ws_size,
                              hipStream_t stream) {
    const float* x    = (const float*)d_in[0];
    const float* h0   = (const float*)d_in[1];
    const float* c0   = (const float*)d_in[2];
    const float* W0   = (const float*)d_in[3];
    const float* b0   = (const float*)d_in[4];
    const float* Wl   = (const float*)d_in[5];
    const float* bl   = (const float*)d_in[6];
    const float* Wout = (const float*)d_in[7];
    const float* bout = (const float*)d_in[8];
    float* out = (float*)d_out;

    char* ws = (char*)d_ws;
    size_t off = 0;
    auto alloc = [&](size_t bytes) {
        size_t r = off;
        off = (off + bytes + 255) & ~(size_t)255;
        return r;
    };
    half_t* WT0   = (half_t*)(ws + alloc((size_t)4096 * 1536 * 2));
    half_t* WT123 = (half_t*)(ws + alloc((size_t)3 * 4096 * 2048 * 2));
    half_t* Zx    = (half_t*)(ws + alloc((size_t)16384 * 4096 * 2));
    half_t* hsA   = (half_t*)(ws + alloc((size_t)16384 * 1024 * 2));
    half_t* hsB   = (half_t*)(ws + alloc((size_t)16384 * 1024 * 2));
    half_t* h_buf = (half_t*)(ws + alloc((size_t)2 * 32 * 1024 * 2));
    int*    cnt   = (int*)(ws + alloc((size_t)4 * 512 * 16 * 4));

    // weight converts (every call; inputs are restored each call)
    wconv_t<<<dim3(128, 48, 1), dim3(32, 8), 0, stream>>>(W0, WT0, 1536);
    wconv_t<<<dim3(128, 64, 3), dim3(32, 8), 0, stream>>>(Wl, WT123, 2048);
    init_cnt<<<128, 256, 0, stream>>>(cnt, 4 * 512 * 16);

    const size_t recLds = (size_t)(2 * 32 * 1032) * 2 + (size_t)32 * 33 * 4;  // 136320 B

    half_t* hs_bufs[2] = {hsA, hsB};
    const void* cur_in = (const void*)x;
    for (int l = 0; l < 4; ++l) {
        const half_t* WTl = (l == 0) ? WT0 : (WT123 + (size_t)(l - 1) * 4096 * 2048);
        int Kfull = (l == 0) ? 1536 : 2048;
        int Din = (l == 0) ? 512 : 1024;
        const float* bias = (l == 0) ? b0 : (bl + (size_t)(l - 1) * 4096);
        half_t* hs_out = hs_bufs[l & 1];  // l0->A, l1->B, l2->A, l3->B

        hinit<<<128, 256, 0, stream>>>(h0 + (size_t)l * 32768, h_buf);
        xproj_gemm<<<dim3(32, 128), 256, 0, stream>>>(cur_in, (l == 0) ? 0 : 1, WTl, Kfull, Din, Zx);
        lstm_rec<<<NWG_REC, 256, recLds, stream>>>(WTl, Kfull, Din, bias, Zx,
                                                   c0 + (size_t)l * 32768, h_buf, hs_out,
                                                   cnt + (size_t)l * 512 * 16);
        cur_in = (const void*)hs_out;
    }
    head_gemm<<<dim3(32, 4), 256, 0, stream>>>(hs_bufs[1], Wout, bout, out);
}

// Round 3
// 4102.135 us; speedup vs baseline: 16.5571x; 6.5355x over previous
//
#include <hip/hip_runtime.h>
#include <stdint.h>
#include <stddef.h>

typedef _Float16 half_t;
typedef __attribute__((ext_vector_type(8))) _Float16 f16x8;
typedef __attribute__((ext_vector_type(16))) float f32x16;
typedef unsigned long long u64;

#define TSEQ 512
#define NSTAGE 515            // 512 + 3 pipeline fill
#define SLOT 32768            // halfs per h slot (32 b x 1024 h)
#define LSTRIDE ((size_t)513 * SLOT)

__device__ __forceinline__ float sigmoidf_(float x) { return 1.f / (1.f + __expf(-x)); }
__device__ __forceinline__ float tanhf_(float x) { return 1.f - 2.f / (__expf(2.f * x) + 1.f); }

__device__ __forceinline__ void async_copy16(const void* g, void* l) {
    __builtin_amdgcn_global_load_lds((const __attribute__((address_space(1))) void*)g,
                                     (__attribute__((address_space(3))) void*)l, 16, 0, 0);
}

// ---- pack weights into per-CU, per-wave MFMA B-fragment order, f32 -> f16 ----
// dest idx = ((((l*64+cu)*4+kq)*2+nt)*32+c)*64+lane, 8 halfs each (k = kq*512+c*16+(lane>>5)*8+j)
// n' = nt*32+(lane&31): gate g = n'>>4, hcol = n'&15, n_glob = g*1024+cu*16+hcol
// Layer 0 K-map: k<512 -> W0 row k (x); 512<=k<1024 -> zero; k>=1024 -> W0 row k-512 (h).
__global__ void wconv_pack(const float* __restrict__ W0, const float* __restrict__ Wl,
                           half_t* __restrict__ WTp) {
    int idx = blockIdx.x * 256 + threadIdx.x;  // 0 .. 2^22-1
    int lane = idx & 63, c = (idx >> 6) & 31, nt = (idx >> 11) & 1;
    int kq = (idx >> 12) & 3, cu = (idx >> 14) & 63, l = idx >> 20;
    int np = nt * 32 + (lane & 31);
    int n = (np >> 4) * 1024 + cu * 16 + (np & 15);
    int kbase = kq * 512 + c * 16 + (lane >> 5) * 8;
    half_t tmp[8];
#pragma unroll
    for (int j = 0; j < 8; ++j) {
        int k = kbase + j;
        float v;
        if (l == 0) {
            if (k < 512) v = W0[(size_t)k * 4096 + n];
            else if (k < 1024) v = 0.f;
            else v = W0[(size_t)(k - 512) * 4096 + n];
        } else {
            v = Wl[((size_t)(l - 1) * 2048 + k) * 4096 + n];
        }
        tmp[j] = (half_t)v;
    }
    *(int4*)(WTp + (size_t)idx * 8) = *(int4*)tmp;
}

// ---- x f32 [32 b][512 t][512 k] -> xb f16 [t][128 c][32 b][8 j], zeros for c>=64 ----
__global__ void xconv(const float* __restrict__ x, half_t* __restrict__ xb) {
    int idx = blockIdx.x * 256 + threadIdx.x;  // 0 .. 2^21-1
    int b = idx & 31, c = (idx >> 5) & 127, t = idx >> 12;
    half_t tmp[8];
#pragma unroll
    for (int j = 0; j < 8; ++j)
        tmp[j] = (c < 64) ? (half_t)x[((size_t)b * 512 + t) * 512 + c * 8 + j] : (half_t)0.f;
    *(int4*)(xb + (size_t)idx * 8) = *(int4*)tmp;
}

// ---- h0 f32 [l][32 b][1024] -> h_out[l] slot 0 blocked [c][b][j] ----
__global__ void hinit(const float* __restrict__ h0, half_t* __restrict__ hO) {
    int idx = blockIdx.x * 256 + threadIdx.x;  // 0..16383
    int b = idx & 31, c = (idx >> 5) & 127, l = idx >> 12;
    half_t tmp[8];
#pragma unroll
    for (int j = 0; j < 8; ++j) tmp[j] = (half_t)h0[(size_t)l * 32768 + b * 1024 + c * 8 + j];
    *(int4*)(hO + (size_t)l * LSTRIDE + (size_t)(c * 32 + b) * 8) = *(int4*)tmp;
}

__global__ void init_flags(int* f, int n) {
    int i = blockIdx.x * blockDim.x + threadIdx.x;
    if (i < n) f[i] = 0;
}

// ---- persistent pipelined LSTM: 256 WGs (1/CU) x 512 threads (8 waves) ----
// WG wg: layer l = wg>>6, cu = wg&63 owns h-cols [cu*16, cu*16+16) of layer l.
// Wave wid: kq = wid>>1 (K quarter of 512), nt = wid&1 (32-col half of the 64 z-cols).
// Per stage s, layer l computes its step t=s-l: z = [x_in(1024); h_prev(1024)] @ W.
__global__ void __launch_bounds__(512, 2) lstm_pipe(
        const half_t* __restrict__ WTp, const half_t* __restrict__ xb,
        const float* __restrict__ b0, const float* __restrict__ bl,
        const float* __restrict__ c0, half_t* __restrict__ hO,
        int* __restrict__ flags) {
    __shared__ char smem[133120];  // 128K A-region (aliased by zbuf) + 1K hbuf
    half_t* A_lds = (half_t*)smem;                  // [256 chunk8][32 b][8 j] halfs
    float* zbuf = (float*)smem;                     // alias: [4 kq][32 b][68] f32
    half_t* hbuf = (half_t*)(smem + 131072);        // [512] halfs, dest-linear

    const int tid = threadIdx.x;
    const int wg = blockIdx.x;
    const int l = wg >> 6, cu = wg & 63;
    const int lane = tid & 63, wid = tid >> 6;
    const int kq = wid >> 1, nt = wid & 1;

    // ---- B fragments: register-stationary for the whole sequence ----
    f16x8 bfr[32];
    {
        const half_t* wp = WTp + (size_t)(((wg * 4 + kq) * 2 + nt) * 32) * 512 + (size_t)lane * 8;
#pragma unroll
        for (int c = 0; c < 32; ++c) bfr[c] = *(const f16x8*)(wp + (size_t)c * 512);
    }

    // ---- gate-phase mapping ----
    const int b = tid & 31, hc = tid >> 5;  // b in [0,32), hc in [0,16)
    const int colg = cu * 16 + hc;
    const float* bias = (l == 0) ? b0 : (bl + (size_t)(l - 1) * 4096);
    const float bi = bias[colg], bf = bias[1024 + colg];
    const float bg = bias[2048 + colg], bo = bias[3072 + colg];
    float c_reg = c0[(size_t)l * 32768 + b * 1024 + colg];

    half_t* houtl = hO + (size_t)l * LSTRIDE;
    const half_t* hin_base = (l == 0) ? xb : (hO + (size_t)(l - 1) * LSTRIDE);

    for (int s = 0; s < NSTAGE; ++s) {
        if (s > 0) {
            if (tid < 256) {
                while (__hip_atomic_load(&flags[tid * 16], __ATOMIC_RELAXED,
                                         __HIP_MEMORY_SCOPE_AGENT) < s)
                    __builtin_amdgcn_s_sleep(2);
            }
            __syncthreads();  // B1: all inputs of stage s-1 visible
        }
        const int t = s - l;
        if (t >= 0 && t < TSEQ) {
            // ---- A staging: waves 0-3 stage x-part (64KB), waves 4-7 h-part (64KB) ----
            {
                const half_t* src = (wid < 4)
                    ? ((l == 0) ? (xb + (size_t)t * SLOT) : (hin_base + (size_t)(t + 1) * SLOT))
                    : (houtl + (size_t)t * SLOT);
                int part = (wid & 3) * 8192;  // halfs within the 64KB half-region
                char* dst0 = smem + wid * 16384;
#pragma unroll
                for (int c2 = 0; c2 < 16; ++c2)
                    async_copy16(src + part + c2 * 512 + lane * 8, dst0 + c2 * 1024);
            }
            __syncthreads();  // B2: staging complete (vmcnt drained)
            // ---- MFMA: 32 chunks of 32x32x16, K quarter kq ----
            f32x16 acc;
#pragma unroll
            for (int r = 0; r < 16; ++r) acc[r] = 0.f;
            {
                const half_t* ap = A_lds + (size_t)(kq * 64 + (lane >> 5)) * 256 + (lane & 31) * 8;
#pragma unroll
                for (int c = 0; c < 32; ++c) {
                    f16x8 a = *(const f16x8*)(ap + (size_t)c * 512);
                    acc = __builtin_amdgcn_mfma_f32_32x32x16_f16(a, bfr[c], acc, 0, 0, 0);
                }
            }
            __syncthreads();  // B3: all A reads done; zbuf may alias A region
            {
                int col = nt * 32 + (lane & 31);
#pragma unroll
                for (int r = 0; r < 16; ++r) {
                    int row = (r & 3) + 8 * (r >> 2) + 4 * (lane >> 5);
                    zbuf[(kq * 32 + row) * 68 + col] = acc[r];
                }
            }
            __syncthreads();  // B4: partials ready
            // ---- gates: thread (b, hc) ----
            {
                float zi = bi, zf = bf, zg = bg, zo = bo;
#pragma unroll
                for (int q = 0; q < 4; ++q) {
                    const float* zr = zbuf + (q * 32 + b) * 68;
                    zi += zr[hc];
                    zf += zr[16 + hc];
                    zg += zr[32 + hc];
                    zo += zr[48 + hc];
                }
                c_reg = sigmoidf_(zf) * c_reg + sigmoidf_(zi) * tanhf_(zg);
                float h = sigmoidf_(zo) * tanhf_(c_reg);
                hbuf[(hc >> 3) * 256 + b * 8 + (hc & 7)] = (half_t)h;
            }
            __syncthreads();  // B5: hbuf complete
            // ---- publish h slot t+1 (device-visible sc1 stores, 8B each) ----
            if (tid < 128) {
                u64 v = ((const u64*)hbuf)[tid];
                u64* dst = (u64*)(houtl + (size_t)(t + 1) * SLOT) + cu * 128 + tid;
                __hip_atomic_store(dst, v, __ATOMIC_RELAXED, __HIP_MEMORY_SCOPE_AGENT);
            }
        }
        __syncthreads();  // B6: h stores drained (each wave's vmcnt) before flag post
        if (s < NSTAGE - 1 && tid == 0)
            __hip_atomic_store(&flags[wg * 16], s + 1, __ATOMIC_RELEASE,
                               __HIP_MEMORY_SCOPE_AGENT);
    }
}

// ---- head: out[b][o] = sum_k h_last[b][k] * Wout[k][o] + bout[o] ----
// h_last = hO layer3 slot 512, blocked [k>>3][b][k&7]
__global__ void head_gemm(const half_t* __restrict__ hO, const float* __restrict__ Wout,
                          const float* __restrict__ bout, float* __restrict__ out) {
    int o = blockIdx.x * 32 + (threadIdx.x & 31);
    int b = blockIdx.y * 8 + (threadIdx.x >> 5);
    const half_t* h = hO + (size_t)3 * LSTRIDE + (size_t)512 * SLOT + b * 8;
    float acc = 0.f;
    for (int kb = 0; kb < 128; ++kb) {
        const half_t* hp = h + (size_t)kb * 256;
#pragma unroll
        for (int j = 0; j < 8; ++j)
            acc += (float)hp[j] * Wout[(size_t)(kb * 8 + j) * 1024 + o];
    }
    out[b * 1024 + o] = acc + bout[o];
}

extern "C" void kernel_launch(void* const* d_in, const int* in_sizes, int n_in,
                              void* d_out, int out_size, void* d_ws, size_t ws_size,
                              hipStream_t stream) {
    const float* x    = (const float*)d_in[0];
    const float* h0   = (const float*)d_in[1];
    const float* c0   = (const float*)d_in[2];
    const float* W0   = (const float*)d_in[3];
    const float* b0   = (const float*)d_in[4];
    const float* Wl   = (const float*)d_in[5];
    const float* bl   = (const float*)d_in[6];
    const float* Wout = (const float*)d_in[7];
    const float* bout = (const float*)d_in[8];
    float* out = (float*)d_out;

    char* ws = (char*)d_ws;
    size_t off = 0;
    auto alloc = [&](size_t bytes) {
        size_t r = off;
        off = (off + bytes + 255) & ~(size_t)255;
        return r;
    };
    half_t* WTp = (half_t*)(ws + alloc((size_t)4 * 64 * 131072 * 2));  // 67.1 MB
    half_t* xb  = (half_t*)(ws + alloc((size_t)512 * SLOT * 2));       // 33.6 MB
    half_t* hO  = (half_t*)(ws + alloc((size_t)4 * LSTRIDE * 2));      // 134.5 MB
    int* flags  = (int*)(ws + alloc((size_t)256 * 16 * 4));

    wconv_pack<<<16384, 256, 0, stream>>>(W0, Wl, WTp);
    xconv<<<8192, 256, 0, stream>>>(x, xb);
    hinit<<<64, 256, 0, stream>>>(h0, hO);
    init_flags<<<16, 256, 0, stream>>>(flags, 256 * 16);

    lstm_pipe<<<256, 512, 0, stream>>>(WTp, xb, b0, bl, c0, hO, flags);

    head_gemm<<<dim3(32, 4), 256, 0, stream>>>(hO, Wout, bout, out);
}